// Round 3
// baseline (94.300 us; speedup 1.0000x reference)
//
#include <hip/hip_runtime.h>
#include <hip/hip_bf16.h>

// MOLELinear: out[n,o] = sum_i x[n,i] * (sum_e coef[b[n],e] * W[e,o,i]) + bias[o]
//
// R3 structure:
//   K1: mixed_W[s][o][i] = sum_e coef[s][e]*W[e][o][i] -> bf16 in d_ws.
//       coef staged through LDS; W chunk held in registers for 8 systems.
//   K2: grouped GEMM over sorted batch_indices, LDS-free, barrier-free.
//       x loads and out stores are NON-TEMPORAL (pure streams, keep L2 for
//       the Wm working set); Wm/bias/bidx use the normal cached path.

#define NE 16   // experts
#define NF 64   // in = out features

typedef __attribute__((ext_vector_type(8))) short  s16x8;   // 8 bf16 = 4 VGPR
typedef __attribute__((ext_vector_type(4))) float  f32x4;

// ---------------- Kernel 1: mix expert weights -> bf16 ----------------
__global__ __launch_bounds__(256) void mix_weights_kernel(
    const float* __restrict__ coef,      // [S][NE]
    const float* __restrict__ W,         // [NE][4096]
    __hip_bfloat16* __restrict__ Wm)     // [S][4096]
{
    const int idx = (blockIdx.x << 8) + threadIdx.x;   // 0..4095
    const int s0  = blockIdx.y << 3;                   // 8 systems per block

    __shared__ float c[8 * NE];
    if (threadIdx.x < 8 * NE) c[threadIdx.x] = coef[s0 * NE + threadIdx.x];

    float w[NE];
#pragma unroll
    for (int e = 0; e < NE; ++e) w[e] = W[e * 4096 + idx];
    __syncthreads();

#pragma unroll
    for (int si = 0; si < 8; ++si) {
        float acc = 0.f;
#pragma unroll
        for (int e = 0; e < NE; ++e) acc += c[si * NE + e] * w[e];
        Wm[(s0 + si) * 4096 + idx] = __float2bfloat16(acc);
    }
}

__device__ __forceinline__ s16x8 cvt_bf16x8(const f32x4 a, const f32x4 b) {
    union { __hip_bfloat16 h[8]; s16x8 v; } u;
#pragma unroll
    for (int i = 0; i < 4; ++i) {
        u.h[i]     = __float2bfloat16(a[i]);
        u.h[4 + i] = __float2bfloat16(b[i]);
    }
    return u.v;
}

// ---------------- Kernel 2: grouped GEMM, LDS-free ----------------
__global__ __launch_bounds__(256) void mole_main(
    const float* __restrict__ x,            // [N][64]
    const int*   __restrict__ bidx,         // [N] sorted
    const __hip_bfloat16* __restrict__ Wm,  // [S][64][64]
    const float* __restrict__ bias,         // [64]
    float*       __restrict__ out,          // [N][64]
    int N)
{
    const int tid  = threadIdx.x;
    const int wv   = tid >> 6;              // wave 0..3 -> 16-atom subtile
    const int lane = tid & 63;
    const int mrow = lane & 15;             // m (A row) and n (B col) index
    const int quad = lane >> 4;             // k-subblock / C row group
    const int t0   = blockIdx.x << 6;       // first atom of block
    const int myrow = t0 + (wv << 4) + mrow;  // this lane's A-frag atom

    // ---- A fragments straight from global x (fp32 -> bf16 in regs)
    // A[m=mrow][k=quad*8+j] for k-step 0 (cols 0..31) and 1 (cols 32..63)
    f32x4 xa0, xa1, xb0, xb1;
    int row_sys;
    if (myrow < N) {
        const f32x4* p = (const f32x4*)(x + (size_t)myrow * NF);
        xa0 = __builtin_nontemporal_load(p + quad * 2);
        xa1 = __builtin_nontemporal_load(p + quad * 2 + 1);
        xb0 = __builtin_nontemporal_load(p + 8 + quad * 2);
        xb1 = __builtin_nontemporal_load(p + 8 + quad * 2 + 1);
        row_sys = bidx[myrow];
    } else {
        xa0 = xa1 = xb0 = xb1 = (f32x4){0.f, 0.f, 0.f, 0.f};
        row_sys = -1;
    }
    const s16x8 a0 = cvt_bf16x8(xa0, xa1);
    const s16x8 a1 = cvt_bf16x8(xb0, xb1);

    // systems spanned by this block (sorted indices -> contiguous range)
    const int s0 = bidx[t0];
    const int s1 = bidx[min(t0 + 63, N - 1)];

    // acc[nt][r] = out[t0 + wv*16 + quad*4 + r][nt*16 + mrow]
    f32x4 acc[4];
#pragma unroll
    for (int nt = 0; nt < 4; ++nt) {
        const float bv = bias[nt * 16 + mrow];
        acc[nt] = (f32x4){bv, bv, bv, bv};
    }

    const s16x8 ZV = {0, 0, 0, 0, 0, 0, 0, 0};
    for (int s = s0; s <= s1; ++s) {
        const s16x8 am0 = (row_sys == s) ? a0 : ZV;
        const s16x8 am1 = (row_sys == s) ? a1 : ZV;
        const __hip_bfloat16* wp = Wm + ((size_t)s << 12);
#pragma unroll
        for (int nt = 0; nt < 4; ++nt) {
            // B[k=quad*8+j][n=mrow] = Wm[s][o=nt*16+mrow][k]  (cached: L1/L2-hot)
            const s16x8 b0 = *(const s16x8*)(wp + (nt * 16 + mrow) * NF + quad * 8);
            const s16x8 b1 = *(const s16x8*)(wp + (nt * 16 + mrow) * NF + 32 + quad * 8);
            acc[nt] = __builtin_amdgcn_mfma_f32_16x16x32_bf16(am0, b0, acc[nt], 0, 0, 0);
            acc[nt] = __builtin_amdgcn_mfma_f32_16x16x32_bf16(am1, b1, acc[nt], 0, 0, 0);
        }
    }

    // Epilogue: C/D layout col(n)=lane&15, row(m)=quad*4+reg
    // Per store instr the wave writes 4 rows x 64B contiguous segments.
#pragma unroll
    for (int nt = 0; nt < 4; ++nt) {
#pragma unroll
        for (int r = 0; r < 4; ++r) {
            const int arow = t0 + (wv << 4) + (quad << 2) + r;
            if (arow < N)
                __builtin_nontemporal_store(acc[nt][r],
                    out + (size_t)arow * NF + nt * 16 + mrow);
        }
    }
}

extern "C" void kernel_launch(void* const* d_in, const int* in_sizes, int n_in,
                              void* d_out, int out_size, void* d_ws, size_t ws_size,
                              hipStream_t stream) {
    const float* x    = (const float*)d_in[0];
    const float* coef = (const float*)d_in[1];
    const int*   bidx = (const int*)d_in[2];
    const float* W    = (const float*)d_in[3];
    const float* bias = (const float*)d_in[4];
    float* out = (float*)d_out;

    const int N = in_sizes[2];            // number of atoms (100000)

    __hip_bfloat16* Wm = (__hip_bfloat16*)d_ws;   // [32][64][64] bf16 = 256 KB

    mix_weights_kernel<<<dim3(16, 4), 256, 0, stream>>>(coef, W, Wm);

    const int nblocks = (N + 63) / 64;
    mole_main<<<nblocks, 256, 0, stream>>>(x, bidx, Wm, bias, out, N);
}